// Round 1
// baseline (111.970 us; speedup 1.0000x reference)
//
#include <hip/hip_runtime.h>

// ---------------- problem constants ----------------
#define NBLK   98304     // 8*3*64*64 total 8x8 blocks
#define NPB    12288     // blocks per batch (3*64*64)
#define HW     512
#define NUMBITS 4096
#define RANK0  29490ULL  // floor(0.3*(NBLK-1))
#define RANK1  29491ULL
#define STEGO_N 6291456  // 8*3*512*512

// ---------------- DCT matrix as compile-time constants ----------------
struct DTab { double d[8][8]; };

constexpr double CT_[9] = {
  1.0,
  0.98078528040323044913,
  0.92387953251128675613,
  0.83146961230254523708,
  0.70710678118654752440,
  0.55557023301960222474,
  0.38268343236508977173,
  0.19509032201612826785,
  0.0
};
constexpr double cospi16(int m){           // cos(pi*m/16), m >= 0
  int r = m % 32;
  return (r<=8) ? CT_[r] : (r<=16) ? -CT_[16-r] : (r<=24) ? -CT_[r-16] : CT_[32-r];
}
constexpr DTab make_dtab(){
  DTab t{};
  for(int k=0;k<8;k++) for(int n=0;n<8;n++){
    double s = (k==0) ? 0.35355339059327376220 : 0.5; // sqrt(1/8), sqrt(2/8)
    t.d[k][n] = s * cospi16((2*n+1)*k);
  }
  return t;
}
constexpr DTab DT = make_dtab();

constexpr unsigned long long make_fmask(){ // bit u*8+v set iff 3 <= u+v <= 8
  unsigned long long m = 0;
  for(int u=0;u<8;u++) for(int v=0;v<8;v++){
    int s=u+v; if(s>=3 && s<=8) m |= (1ULL << (u*8+v));
  }
  return m;
}
constexpr unsigned long long FMASK = make_fmask();  // 37 bits set

// ---------------- kernels ----------------

// per-block fp64 variance + global min/max (as u64 bits; var>=0 so order-preserving)
__global__ __launch_bounds__(256) void k_stats(const float* __restrict__ cover,
    double* __restrict__ var, unsigned long long* __restrict__ mnb,
    unsigned long long* __restrict__ mxb){
  int tid = threadIdx.x;
  int i = blockIdx.x*256 + tid;            // block id over (b,c,n,m)
  int m = i & 63, n = (i>>6)&63, bc = i>>12;
  const float* p = cover + ((size_t)bc*HW + (size_t)n*8)*HW + (size_t)m*8;
  double s1=0.0, s2=0.0;
#pragma unroll
  for(int r=0;r<8;r++){
    const float4* q = (const float4*)(p + (size_t)r*HW);
    float4 a = q[0], b = q[1];
    double x;
    x=(double)a.x; s1+=x; s2+=x*x;
    x=(double)a.y; s1+=x; s2+=x*x;
    x=(double)a.z; s1+=x; s2+=x*x;
    x=(double)a.w; s1+=x; s2+=x*x;
    x=(double)b.x; s1+=x; s2+=x*x;
    x=(double)b.y; s1+=x; s2+=x*x;
    x=(double)b.z; s1+=x; s2+=x*x;
    x=(double)b.w; s1+=x; s2+=x*x;
  }
  double mean = s1*(1.0/64.0);
  double v = s2*(1.0/64.0) - mean*mean;
  if(v < 0.0) v = 0.0;
  var[i] = v;
  unsigned long long bits = (unsigned long long)__double_as_longlong(v);
  __shared__ unsigned long long smn[256], smx[256];
  smn[tid]=bits; smx[tid]=bits;
  __syncthreads();
  for(int off=128; off>0; off>>=1){
    if(tid<off){
      if(smn[tid+off] < smn[tid]) smn[tid]=smn[tid+off];
      if(smx[tid+off] > smx[tid]) smx[tid]=smx[tid+off];
    }
    __syncthreads();
  }
  if(tid==0){ atomicMin(mnb, smn[0]); atomicMax(mxb, smx[0]); }
}

// radix-select histogram round r (dual rank-state). LDS hist to tame hot bins.
__global__ __launch_bounds__(1024) void k_hist(const double* __restrict__ var,
    unsigned* __restrict__ bins, const unsigned long long* __restrict__ pref,
    int r, int shift, int highshift, int nbins){
  __shared__ unsigned h[4096];
  int tid = threadIdx.x;
  for(int j=tid;j<4096;j+=1024) h[j]=0;
  __syncthreads();
  int i = blockIdx.x*1024 + tid;
  unsigned long long bits = (unsigned long long)__double_as_longlong(var[i]);
  unsigned bin = (unsigned)((bits>>shift) & (unsigned long long)(nbins-1));
#pragma unroll
  for(int s=0;s<2;s++){
    bool match;
    if(r==0) match = true;
    else { unsigned long long pf = pref[s]; match = ((bits>>highshift)==(pf>>highshift)); }
    if(match) atomicAdd(&h[s*2048+bin], 1u);
  }
  __syncthreads();
  for(int j=tid;j<4096;j+=1024){
    unsigned v=h[j];
    if(v) atomicAdd(&bins[r*4096+j], v);
  }
}

// pick the digit containing each remaining rank; at last round compute thr/mn/d
__global__ __launch_bounds__(1024) void k_pick(const unsigned* __restrict__ bins,
    unsigned long long* __restrict__ pref, unsigned long long* __restrict__ rank,
    int r, int shift, int nbins, int last,
    const unsigned long long* __restrict__ mnb, const unsigned long long* __restrict__ mxb,
    double* __restrict__ scal){
  __shared__ unsigned sb[1024];
  int tid = threadIdx.x;
  for(int s=0;s<2;s++){
    unsigned long long rk = (r==0) ? (s ? RANK1 : RANK0) : rank[s];
    const unsigned* bb = bins + r*4096 + s*2048;
    unsigned a0 = (2*tid   < nbins) ? bb[2*tid]   : 0u;
    unsigned a1 = (2*tid+1 < nbins) ? bb[2*tid+1] : 0u;
    unsigned part = a0+a1;
    sb[tid]=part; __syncthreads();
    for(int off=1;off<1024;off<<=1){
      unsigned add = (tid>=off)? sb[tid-off] : 0u;
      __syncthreads();
      sb[tid]+=add;
      __syncthreads();
    }
    unsigned incl=sb[tid], excl=incl-part;
    if(rk >= (unsigned long long)excl && rk < (unsigned long long)incl){
      int j; unsigned base;
      if(rk < (unsigned long long)excl + a0){ j=2*tid;   base=excl; }
      else                                  { j=2*tid+1; base=excl+a0; }
      unsigned long long p = (r==0) ? 0ULL : pref[s];
      pref[s] = p | ((unsigned long long)j << shift);
      rank[s] = rk - base;
    }
    __syncthreads();
  }
  if(last && tid==0){
    double mn = __longlong_as_double((long long)*mnb);
    double mx = __longlong_as_double((long long)*mxb);
    double A  = __longlong_as_double((long long)pref[0]); // s[29490]
    double Bv = __longlong_as_double((long long)pref[1]); // s[29491]
    double d  = mx - mn + 1e-8;
    double vnA = (A-mn)/d, vnB = (Bv-mn)/d;
    scal[0] = vnA + 0.9*(vnB-vnA);  // thr (any frac in (0,1) equivalent)
    scal[1] = mn;
    scal[2] = d;
  }
}

// texture mask + per-1024 exclusive prefix
__global__ __launch_bounds__(1024) void k_tex(const double* __restrict__ var,
    const double* __restrict__ scal, int* __restrict__ flags, int* __restrict__ P,
    int* __restrict__ bsums){
  __shared__ int sb[1024];
  int tid = threadIdx.x;
  int i = blockIdx.x*1024 + tid;
  double thr=scal[0], mn=scal[1], d=scal[2];
  int f = ((var[i]-mn)/d > thr) ? 1 : 0;
  sb[tid]=f; __syncthreads();
  for(int off=1;off<1024;off<<=1){
    int add = (tid>=off)? sb[tid-off] : 0;
    __syncthreads();
    sb[tid]+=add;
    __syncthreads();
  }
  int incl = sb[tid];
  flags[i]=f; P[i]=incl-f;
  if(tid==1023) bsums[blockIdx.x]=incl;
}

__global__ void k_scan2(const int* __restrict__ bsums, int* __restrict__ O){
  if(threadIdx.x==0){
    int c=0;
    for(int j=0;j<96;j++){ O[j]=c; c+=bsums[j]; }
  }
}

// redo only blocks that contain eligible coefficients (~111 blocks), full fp64
__global__ __launch_bounds__(256) void k_fix(const float* __restrict__ cover,
    const int* __restrict__ secret, const int* __restrict__ flags,
    const int* __restrict__ P, const int* __restrict__ O, float* __restrict__ out){
  int i = blockIdx.x*256 + threadIdx.x;
  if(!flags[i]) return;
  int S = O[i>>10] + P[i];              // # selected blocks strictly before this one
  if(37*S >= NUMBITS) return;           // no eligible coefficient in this block
  int m = i & 63, n = (i>>6)&63, bc = i>>12;
  int b = i / NPB;
  const float* p  = cover + ((size_t)bc*HW + (size_t)n*8)*HW + (size_t)m*8;
  float*       po = out   + ((size_t)bc*HW + (size_t)n*8)*HW + (size_t)m*8;
  double X[8][8];
#pragma unroll
  for(int r=0;r<8;r++){
#pragma unroll
    for(int j=0;j<8;j++) X[r][j] = (double)p[(size_t)r*HW + j];
  }
  // forward: T = X * D^T (row-wise in place)
#pragma unroll
  for(int r=0;r<8;r++){
    double t[8];
#pragma unroll
    for(int v=0;v<8;v++){
      double a=0.0;
#pragma unroll
      for(int j=0;j<8;j++) a += X[r][j]*DT.d[v][j];
      t[v]=a;
    }
#pragma unroll
    for(int v=0;v<8;v++) X[r][v]=t[v];
  }
  // C = D * T (column-wise in place)
#pragma unroll
  for(int v=0;v<8;v++){
    double t[8];
#pragma unroll
    for(int u=0;u<8;u++){
      double a=0.0;
#pragma unroll
      for(int k=0;k<8;k++) a += DT.d[u][k]*X[k][v];
      t[u]=a;
    }
#pragma unroll
    for(int u=0;u<8;u++) X[u][v]=t[u];
  }
  // embedding on coefficients
  size_t mapBase = (size_t)STEGO_N + (size_t)i*64;
  int fp = 0;
#pragma unroll
  for(int u=0;u<8;u++){
#pragma unroll
    for(int v=0;v<8;v++){
      int t = u*8+v;
      bool sel = (FMASK>>t)&1ULL;
      float mv = 0.0f;
      if(sel){
        int ord = 37*S + fp;
        if(ord < NUMBITS){
          mv = 1.0f;
          double c = X[u][v];
          double rnd = rint(c);                 // round half-to-even == jnp.round
          double lsb = fabs(fmod(rnd, 2.0));    // 0 or 1
          int bit = secret[(size_t)b*NUMBITS + ord];
          if(((int)lsb) != bit){
            X[u][v] = c + ((c>=0.0)?1.0:-1.0)*(2.0*(double)bit-1.0)*0.5;
          }
        }
        fp++;
      }
      out[mapBase + t] = mv;
    }
  }
  // inverse: T2 = D^T * M (column-wise in place)
#pragma unroll
  for(int v=0;v<8;v++){
    double t[8];
#pragma unroll
    for(int r=0;r<8;r++){
      double a=0.0;
#pragma unroll
      for(int u=0;u<8;u++) a += DT.d[u][r]*X[u][v];
      t[r]=a;
    }
#pragma unroll
    for(int r=0;r<8;r++) X[r][v]=t[r];
  }
  // pixels = T2 * D, write
#pragma unroll
  for(int r=0;r<8;r++){
    double t[8];
#pragma unroll
    for(int k=0;k<8;k++){
      double a=0.0;
#pragma unroll
      for(int l=0;l<8;l++) a += X[r][l]*DT.d[l][k];
      t[k]=a;
    }
#pragma unroll
    for(int k=0;k<8;k++) po[(size_t)r*HW + k] = (float)t[k];
  }
}

// ---------------- host launch ----------------
extern "C" void kernel_launch(void* const* d_in, const int* in_sizes, int n_in,
                              void* d_out, int out_size, void* d_ws, size_t ws_size,
                              hipStream_t stream) {
  const float* cover  = (const float*)d_in[0];
  const int*   secret = (const int*)d_in[1];
  float* out = (float*)d_out;
  char*  ws  = (char*)d_ws;

  // ws layout (bytes)
  double* var   = (double*)(ws);                    // 98304*8   = 786432
  int*    flags = (int*)(ws + 786432);              // 98304*4   -> 1179648
  int*    P     = (int*)(ws + 1179648);             // 98304*4   -> 1572864
  int*    bsums = (int*)(ws + 1572864);             // 96*4      -> 1573248
  int*    O     = (int*)(ws + 1573248);             // 96*4      -> 1573632
  unsigned long long* mnb = (unsigned long long*)(ws + 1573632);  // 8
  unsigned long long* mxb = (unsigned long long*)(ws + 1573640);  // 8
  unsigned* bins = (unsigned*)(ws + 1573648);       // 6*4096*4  = 98304 -> 1671952
  unsigned long long* pref = (unsigned long long*)(ws + 1671952); // [2]
  unsigned long long* rank = (unsigned long long*)(ws + 1671968); // [2]
  double* scal = (double*)(ws + 1671984);           // thr, mn, d

  // init: mn = +inf-bits (0xFF..), mx+bins = 0 (contiguous region)
  hipMemsetAsync(mnb, 0xFF, 8, stream);
  hipMemsetAsync(mxb, 0, 8 + 6*4096*4, stream);

  // fast path: stego = cover, map = 0 (fixed up below for eligible blocks)
  hipMemcpyAsync(out, cover, (size_t)STEGO_N*4, hipMemcpyDeviceToDevice, stream);
  hipMemsetAsync(out + STEGO_N, 0, (size_t)STEGO_N*4, stream);

  k_stats<<<NBLK/256, 256, 0, stream>>>(cover, var, mnb, mxb);

  const int shifts[6] = {53,42,31,20,9,0};
  const int nb[6]     = {2048,2048,2048,2048,2048,512};
  for(int r=0;r<6;r++){
    int highshift = (r==0) ? 64 : shifts[r-1];
    k_hist<<<NBLK/1024, 1024, 0, stream>>>(var, bins, pref, r, shifts[r], highshift, nb[r]);
    k_pick<<<1, 1024, 0, stream>>>(bins, pref, rank, r, shifts[r], nb[r], (r==5)?1:0, mnb, mxb, scal);
  }

  k_tex<<<NBLK/1024, 1024, 0, stream>>>(var, scal, flags, P, bsums);
  k_scan2<<<1, 64, 0, stream>>>(bsums, O);
  k_fix<<<NBLK/256, 256, 0, stream>>>(cover, secret, flags, P, O, out);
}

// Round 2
// 88.382 us; speedup vs baseline: 1.2669x; 1.2669x over previous
//
#include <hip/hip_runtime.h>

// ---------------- problem constants ----------------
#define NBLK   98304     // 8*3*64*64 total 8x8 blocks
#define NPB    12288     // blocks per batch (3*64*64)
#define HW     512
#define NUMBITS 4096
#define RANK0  29490ULL  // floor(0.3*(NBLK-1))
#define RANK1  29491ULL
#define STEGO_N 6291456  // 8*3*512*512
#define ELIG   111       // ceil(4096/37) blocks contain eligible coefficients

// ---------------- DCT matrix as compile-time constants ----------------
struct DTab { double d[8][8]; };

constexpr double CT_[9] = {
  1.0,
  0.98078528040323044913,
  0.92387953251128675613,
  0.83146961230254523708,
  0.70710678118654752440,
  0.55557023301960222474,
  0.38268343236508977173,
  0.19509032201612826785,
  0.0
};
constexpr double cospi16(int m){           // cos(pi*m/16), m >= 0
  int r = m % 32;
  return (r<=8) ? CT_[r] : (r<=16) ? -CT_[16-r] : (r<=24) ? -CT_[r-16] : CT_[32-r];
}
constexpr DTab make_dtab(){
  DTab t{};
  for(int k=0;k<8;k++) for(int n=0;n<8;n++){
    double s = (k==0) ? 0.35355339059327376220 : 0.5; // sqrt(1/8), sqrt(2/8)
    t.d[k][n] = s * cospi16((2*n+1)*k);
  }
  return t;
}
constexpr DTab DT = make_dtab();

constexpr unsigned long long make_fmask(){ // bit u*8+v set iff 3 <= u+v <= 8
  unsigned long long m = 0;
  for(int u=0;u<8;u++) for(int v=0;v<8;v++){
    int s=u+v; if(s>=3 && s<=8) m |= (1ULL << (u*8+v));
  }
  return m;
}
constexpr unsigned long long FMASK = make_fmask();  // 37 bits set

// ---------------- kernels ----------------

// fused: stego = cover (copy), map = 0, per-block fp64 variance
__global__ __launch_bounds__(256) void k_stats(const float* __restrict__ cover,
    float* __restrict__ out, double* __restrict__ var){
  int i = blockIdx.x*256 + threadIdx.x;     // block id over (b,c,n,m)
  int m = i & 63, n = (i>>6)&63, bc = i>>12;
  const float* p  = cover + ((size_t)bc*HW + (size_t)n*8)*HW + (size_t)m*8;
  float*       po = out   + ((size_t)bc*HW + (size_t)n*8)*HW + (size_t)m*8;
  double s1=0.0, s2=0.0;
#pragma unroll
  for(int r=0;r<8;r++){
    const float4* q = (const float4*)(p + (size_t)r*HW);
    float4 a = q[0], b = q[1];
    float4* w = (float4*)(po + (size_t)r*HW);
    w[0]=a; w[1]=b;
    double x;
    x=(double)a.x; s1+=x; s2+=x*x;
    x=(double)a.y; s1+=x; s2+=x*x;
    x=(double)a.z; s1+=x; s2+=x*x;
    x=(double)a.w; s1+=x; s2+=x*x;
    x=(double)b.x; s1+=x; s2+=x*x;
    x=(double)b.y; s1+=x; s2+=x*x;
    x=(double)b.z; s1+=x; s2+=x*x;
    x=(double)b.w; s1+=x; s2+=x*x;
  }
  double mean = s1*(1.0/64.0);
  double v = s2*(1.0/64.0) - mean*mean;
  if(v < 0.0) v = 0.0;
  var[i] = v;
  // zero the embedding map for this block (fixed up later for eligible blocks)
  float4 z = make_float4(0.f,0.f,0.f,0.f);
  float4* pm = (float4*)(out + (size_t)STEGO_N + (size_t)i*64);
#pragma unroll
  for(int j=0;j<16;j++) pm[j] = z;
}

// radix-select histogram round r (dual rank-state). LDS hist to tame hot bins.
__global__ __launch_bounds__(1024) void k_hist(const double* __restrict__ var,
    unsigned* __restrict__ bins, const unsigned long long* __restrict__ pref,
    int r, int shift, int highshift, int nbins){
  __shared__ unsigned h[4096];
  int tid = threadIdx.x;
  for(int j=tid;j<4096;j+=1024) h[j]=0;
  __syncthreads();
  int i = blockIdx.x*1024 + tid;
  unsigned long long bits = (unsigned long long)__double_as_longlong(var[i]);
  unsigned bin = (unsigned)((bits>>shift) & (unsigned long long)(nbins-1));
#pragma unroll
  for(int s=0;s<2;s++){
    bool match;
    if(r==0) match = true;
    else { unsigned long long pf = pref[s]; match = ((bits>>highshift)==(pf>>highshift)); }
    if(match) atomicAdd(&h[s*2048+bin], 1u);
  }
  __syncthreads();
  for(int j=tid;j<4096;j+=1024){
    unsigned v=h[j];
    if(v) atomicAdd(&bins[r*4096+j], v);
  }
}

// pick the digit containing each remaining rank; at last round compute raw thr
__global__ __launch_bounds__(1024) void k_pick(const unsigned* __restrict__ bins,
    unsigned long long* __restrict__ pref, unsigned long long* __restrict__ rank,
    int r, int shift, int nbins, int last, double* __restrict__ scal){
  __shared__ unsigned sb[1024];
  int tid = threadIdx.x;
  for(int s=0;s<2;s++){
    unsigned long long rk = (r==0) ? (s ? RANK1 : RANK0) : rank[s];
    const unsigned* bb = bins + r*4096 + s*2048;
    unsigned a0 = (2*tid   < nbins) ? bb[2*tid]   : 0u;
    unsigned a1 = (2*tid+1 < nbins) ? bb[2*tid+1] : 0u;
    unsigned part = a0+a1;
    sb[tid]=part; __syncthreads();
    for(int off=1;off<1024;off<<=1){
      unsigned add = (tid>=off)? sb[tid-off] : 0u;
      __syncthreads();
      sb[tid]+=add;
      __syncthreads();
    }
    unsigned incl=sb[tid], excl=incl-part;
    if(rk >= (unsigned long long)excl && rk < (unsigned long long)incl){
      int j; unsigned base;
      if(rk < (unsigned long long)excl + a0){ j=2*tid;   base=excl; }
      else                                  { j=2*tid+1; base=excl+a0; }
      unsigned long long p = (r==0) ? 0ULL : pref[s];
      pref[s] = p | ((unsigned long long)j << shift);
      rank[s] = rk - base;
    }
    __syncthreads();
  }
  if(last && tid==0){
    double A  = __longlong_as_double((long long)pref[0]); // s[29490]
    double Bv = __longlong_as_double((long long)pref[1]); // s[29491]
    // selection (var_norm > thr) is monotone-equivalent to var > A + 0.9*(B-A)
    scal[0] = A + 0.9*(Bv - A);
  }
}

// texture mask + per-1024 exclusive prefix (raw-variance threshold)
__global__ __launch_bounds__(1024) void k_tex(const double* __restrict__ var,
    const double* __restrict__ scal, int* __restrict__ flags, int* __restrict__ P,
    int* __restrict__ bsums){
  __shared__ int sb[1024];
  int tid = threadIdx.x;
  int i = blockIdx.x*1024 + tid;
  double thr = scal[0];
  int f = (var[i] > thr) ? 1 : 0;
  sb[tid]=f; __syncthreads();
  for(int off=1;off<1024;off<<=1){
    int add = (tid>=off)? sb[tid-off] : 0;
    __syncthreads();
    sb[tid]+=add;
    __syncthreads();
  }
  int incl = sb[tid];
  flags[i]=f; P[i]=incl-f;
  if(tid==1023) bsums[blockIdx.x]=incl;
}

__global__ void k_scan2(const int* __restrict__ bsums, int* __restrict__ O){
  if(threadIdx.x==0){
    int c=0;
    for(int j=0;j<96;j++){ O[j]=c; c+=bsums[j]; }
  }
}

// write the block index of each of the first ELIG selected blocks
__global__ __launch_bounds__(256) void k_compact(const int* __restrict__ flags,
    const int* __restrict__ P, const int* __restrict__ O, int* __restrict__ list){
  int i = blockIdx.x*256 + threadIdx.x;
  if(!flags[i]) return;
  int S = O[i>>10] + P[i];
  if(S < ELIG) list[S] = i;
}

// one wave per eligible block; lane l owns coefficient/pixel (l>>3, l&7). fp64.
__global__ __launch_bounds__(64) void k_embed(const float* __restrict__ cover,
    const int* __restrict__ secret, const int* __restrict__ list,
    float* __restrict__ out){
  __shared__ double shA[64], shB[64];
  int l = threadIdx.x;
  int S = blockIdx.x;          // list[S] = block id with selected-rank S
  int i = list[S];
  int m = i & 63, n = (i>>6)&63, bc = i>>12, b = i / NPB;
  const float* p  = cover + ((size_t)bc*HW + (size_t)n*8)*HW + (size_t)m*8;
  float*       po = out   + ((size_t)bc*HW + (size_t)n*8)*HW + (size_t)m*8;
  int r = l>>3, c = l&7;
  shA[l] = (double)p[(size_t)r*HW + c];
  __syncthreads();
  // stage1: T1[r][v] = sum_j X[r][j]*D[v][j]   (lane = (r, v=c))
  double a = 0.0;
#pragma unroll
  for(int j=0;j<8;j++) a += shA[r*8+j]*DT.d[c][j];
  shB[l] = a;
  __syncthreads();
  // stage2: C[u][v] = sum_k D[u][k]*T1[k][v]   (lane = (u=r, v=c))
  double coef = 0.0;
#pragma unroll
  for(int k=0;k<8;k++) coef += DT.d[r][k]*shB[k*8+c];
  // embedding
  bool sel = (FMASK>>l)&1ULL;
  float mv = 0.f;
  if(sel){
    int fp  = (int)__popcll(FMASK & ((1ULL<<l)-1ULL));
    int ord = 37*S + fp;
    if(ord < NUMBITS){
      mv = 1.f;
      double rnd = rint(coef);                    // round half-to-even == jnp.round
      int lsb = ((int)fabs(rnd)) & 1;
      int bit = secret[(size_t)b*NUMBITS + ord];
      if(lsb != bit) coef += ((coef>=0.0)?1.0:-1.0)*(2.0*(double)bit-1.0)*0.5;
    }
  }
  out[(size_t)STEGO_N + (size_t)i*64 + l] = mv;
  shA[l] = coef;               // shA free: last read was before previous barrier
  __syncthreads();
  // inv stage1: T2[r][v] = sum_u D[u][r]*M[u][v]   (lane = (r, v=c))
  a = 0.0;
#pragma unroll
  for(int u=0;u<8;u++) a += DT.d[u][r]*shA[u*8+c];
  shB[l] = a;
  __syncthreads();
  // inv stage2: pix[r][k] = sum_q T2[r][q]*D[q][k]   (lane = (r, k=c))
  a = 0.0;
#pragma unroll
  for(int q=0;q<8;q++) a += shB[r*8+q]*DT.d[q][c];
  po[(size_t)r*HW + c] = (float)a;
}

// ---------------- host launch ----------------
extern "C" void kernel_launch(void* const* d_in, const int* in_sizes, int n_in,
                              void* d_out, int out_size, void* d_ws, size_t ws_size,
                              hipStream_t stream) {
  const float* cover  = (const float*)d_in[0];
  const int*   secret = (const int*)d_in[1];
  float* out = (float*)d_out;
  char*  ws  = (char*)d_ws;

  // ws layout (bytes)
  double* var   = (double*)(ws);                    // 98304*8   = 786432
  int*    flags = (int*)(ws + 786432);              // 98304*4   -> 1179648
  int*    P     = (int*)(ws + 1179648);             // 98304*4   -> 1572864
  int*    bsums = (int*)(ws + 1572864);             // 96*4      -> 1573248
  int*    O     = (int*)(ws + 1573248);             // 96*4      -> 1573632
  unsigned* bins = (unsigned*)(ws + 1573632);       // 6*4096*4  = 98304 -> 1671936
  unsigned long long* pref = (unsigned long long*)(ws + 1671936); // [2]
  unsigned long long* rank = (unsigned long long*)(ws + 1671952); // [2]
  double* scal = (double*)(ws + 1671968);           // raw threshold
  int*    list = (int*)(ws + 1671976);              // ELIG ints

  hipMemsetAsync(bins, 0, 6*4096*4, stream);

  // fused copy + map-zero + variance
  k_stats<<<NBLK/256, 256, 0, stream>>>(cover, out, var);

  const int shifts[6] = {53,42,31,20,9,0};
  const int nb[6]     = {2048,2048,2048,2048,2048,512};
  for(int r=0;r<6;r++){
    int highshift = (r==0) ? 64 : shifts[r-1];
    k_hist<<<NBLK/1024, 1024, 0, stream>>>(var, bins, pref, r, shifts[r], highshift, nb[r]);
    k_pick<<<1, 1024, 0, stream>>>(bins, pref, rank, r, shifts[r], nb[r], (r==5)?1:0, scal);
  }

  k_tex<<<NBLK/1024, 1024, 0, stream>>>(var, scal, flags, P, bsums);
  k_scan2<<<1, 64, 0, stream>>>(bsums, O);
  k_compact<<<NBLK/256, 256, 0, stream>>>(flags, P, O, list);
  k_embed<<<ELIG, 64, 0, stream>>>(cover, secret, list, out);
}